// Round 5
// baseline (143.397 us; speedup 1.0000x reference)
//
#include <hip/hip_runtime.h>
#include <hip/hip_bf16.h>

#define B_DIM 16
#define KQ    2048
#define W_DIM 2048
#define D_DIM 128
#define QBLK  64
#define KVB   32
#define NT    (W_DIM / KVB)
#define BUFB  24576

typedef float f2 __attribute__((ext_vector_type(2)));
typedef float f4 __attribute__((ext_vector_type(4)));
typedef float f32x4 __attribute__((ext_vector_type(4)));
typedef __bf16 bf16x8 __attribute__((ext_vector_type(8)));
typedef unsigned short u16x2 __attribute__((ext_vector_type(2)));
typedef unsigned short u16x4 __attribute__((ext_vector_type(4)));
typedef unsigned short u16x8 __attribute__((ext_vector_type(8)));

static __device__ __forceinline__ unsigned short f2bf(float x) {
  __bf16 h = (__bf16)x;
  return __builtin_bit_cast(unsigned short, h);
}

// Per-24KB buffer layout:
//   [0,     8192)  K1: 32 w-rows x 128 bf16, row 256B, byte ^= ((row&7)<<4) @16B gran
//   [8192, 16384)  K2: same
//   [16384,24576)  V:  128 d-rows x 64B; 16B chunk c holds w-set pi_c(j)=16*(j>>2)+4c+(j&3);
//                  stored chunk index = c ^ ((d>>1)&3)
// Two buffers (49152B total); epilogue reuses [0,32768) as 64 q-rows x 128 f32.

__global__ __launch_bounds__(256, 2)
void diffattn(const float* __restrict__ Q1g, const float* __restrict__ Q2g,
              const float* __restrict__ K1g, const float* __restrict__ K2g,
              const float* __restrict__ Vg, const float* __restrict__ lamp,
              float* __restrict__ Og)
{
  __shared__ char smem[2 * BUFB];

  const int tid  = threadIdx.x;
  const int wv   = tid >> 6;
  const int lane = tid & 63;
  const int g    = lane >> 4;
  const int r    = lane & 15;
  const int s    = wv >> 1;   // stream
  const int qh   = wv & 1;    // q half

  const int wg  = blockIdx.x;
  const int swz = (wg & 7) * 64 + (wg >> 3);
  const int qt  = swz & 31;
  const int b   = swz >> 5;
  const int q0  = qt * QBLK;

  const float scale = 0.08838834764831845f;

  // ---- Q fragments (this wave's stream; 32 q-rows = 2 groups)
  const float* Qs = s ? Q2g : Q1g;
  bf16x8 qf[2][4];
#pragma unroll
  for (int qg = 0; qg < 2; ++qg) {
    const float* qp = Qs + ((size_t)b * KQ + q0 + qh * 32 + qg * 16 + r) * D_DIM;
#pragma unroll
    for (int kc = 0; kc < 4; ++kc) {
      const int off = kc * 32 + g * 8;
      f4 lo = *(const f4*)(qp + off);
      f4 hi = *(const f4*)(qp + off + 4);
      bf16x8 tq;
#pragma unroll
      for (int j = 0; j < 4; ++j) {
        tq[j]     = (__bf16)(lo[j] * scale);
        tq[4 + j] = (__bf16)(hi[j] * scale);
      }
      qf[qg][kc] = tq;
    }
  }

  const f32x4 vzero = {0.f, 0.f, 0.f, 0.f};
  f32x4 o[2][8];
#pragma unroll
  for (int qg = 0; qg < 2; ++qg)
#pragma unroll
    for (int dc = 0; dc < 8; ++dc) o[qg][dc] = vzero;

  float m_[2] = {-__builtin_inff(), -__builtin_inff()};
  float l_[2] = {0.f, 0.f};   // per-lane PARTIAL row sums (reduced in epilogue)

  const float* k1base = K1g + (size_t)b * W_DIM * D_DIM;
  const float* k2base = K2g + (size_t)b * W_DIM * D_DIM;
  const float* vbase  = Vg  + (size_t)b * W_DIM * D_DIM;

  // ---- staging constants ----
  const int ks = tid >> 5;
  const int c8 = tid & 31;
  int gk[4], kw[4];
#pragma unroll
  for (int ii = 0; ii < 4; ++ii) {
    const int row = ks * 4 + ii;
    gk[ii] = row * D_DIM + c8 * 4;
    kw[ii] = row * 256 + ((c8 * 8) ^ ((row & 7) << 4));
  }
  const int gsv = tid >> 6;
  const int dd  = tid & 63;
  int gvv[8];
#pragma unroll
  for (int ii = 0; ii < 8; ++ii) {
    const int w = 16 * (ii >> 2) + 4 * gsv + (ii & 3);
    gvv[ii] = w * D_DIM + 2 * dd;
  }
  int vw[2];
#pragma unroll
  for (int jj = 0; jj < 2; ++jj)
    vw[jj] = 16384 + (2 * dd + jj) * 64 + ((gsv ^ (dd & 3)) << 4);

  // ---- compute constants ----
  int koffx[4];
#pragma unroll
  for (int kc = 0; kc < 4; ++kc) koffx[kc] = (kc * 64 + g * 16) ^ ((r & 7) << 4);
  const int kb0 = s * 8192 + r * 256;
  const int vr0 = 16384 + r * 64 + ((g ^ ((r >> 1) & 3)) << 4);

  // bf16-converted staging registers (24 VGPRs)
  u16x4 sk1b[4], sk2b[4];
  u16x2 svb[8];

  auto LOADT = [&](int t) {
    const float* p1 = k1base + (size_t)t * KVB * D_DIM;
    const float* p2 = k2base + (size_t)t * KVB * D_DIM;
    const float* pv = vbase  + (size_t)t * KVB * D_DIM;
#pragma unroll
    for (int ii = 0; ii < 4; ++ii) {
      const f4 x1 = *(const f4*)(p1 + gk[ii]);
      const f4 x2 = *(const f4*)(p2 + gk[ii]);
      sk1b[ii] = (u16x4){ f2bf(x1[0]), f2bf(x1[1]), f2bf(x1[2]), f2bf(x1[3]) };
      sk2b[ii] = (u16x4){ f2bf(x2[0]), f2bf(x2[1]), f2bf(x2[2]), f2bf(x2[3]) };
    }
#pragma unroll
    for (int ii = 0; ii < 8; ++ii) {
      const f2 v = *(const f2*)(pv + gvv[ii]);
      svb[ii] = (u16x2){ f2bf(v[0]), f2bf(v[1]) };
    }
  };

  auto WRITET = [&](char* bufp) {
#pragma unroll
    for (int ii = 0; ii < 4; ++ii) {
      *(u16x4*)(bufp + kw[ii])        = sk1b[ii];
      *(u16x4*)(bufp + 8192 + kw[ii]) = sk2b[ii];
    }
#pragma unroll
    for (int jj = 0; jj < 2; ++jj) {
      u16x8 u = { svb[0][jj], svb[1][jj], svb[2][jj], svb[3][jj],
                  svb[4][jj], svb[5][jj], svb[6][jj], svb[7][jj] };
      *(u16x8*)(bufp + vw[jj]) = u;
    }
  };

  LOADT(0);
  WRITET(smem);
  LOADT(1);
  __syncthreads();

#pragma unroll 1
  for (int t = 0; t < NT; ++t) {
    char* bufc = smem + (t & 1) * BUFB;

    // staging for t+1 overlaps this iter's compute (no barrier in between)
    if (t + 1 < NT) {
      WRITET(smem + ((t + 1) & 1) * BUFB);
      if (t + 2 < NT) LOADT(t + 2);
    }

    // ---- QK^T: S[w][q] for this wave's stream ----
    f32x4 sa[2][2];
    sa[0][0] = vzero; sa[0][1] = vzero; sa[1][0] = vzero; sa[1][1] = vzero;
    __builtin_amdgcn_s_setprio(1);
#pragma unroll
    for (int kc = 0; kc < 4; ++kc) {
      const bf16x8 a0 = *(const bf16x8*)(bufc + kb0 + koffx[kc]);
      const bf16x8 a1 = *(const bf16x8*)(bufc + kb0 + 4096 + koffx[kc]);
#pragma unroll
      for (int qg = 0; qg < 2; ++qg) {
        sa[qg][0] = __builtin_amdgcn_mfma_f32_16x16x32_bf16(a0, qf[qg][kc], sa[qg][0], 0, 0, 0);
        sa[qg][1] = __builtin_amdgcn_mfma_f32_16x16x32_bf16(a1, qf[qg][kc], sa[qg][1], 0, 0, 0);
      }
    }
    __builtin_amdgcn_s_setprio(0);

    // ---- online softmax; P packed into PV A-fragments in-register ----
    bf16x8 pa[2];
#pragma unroll
    for (int qg = 0; qg < 2; ++qg) {
      float tm = fmaxf(fmaxf(fmaxf(sa[qg][0][0], sa[qg][0][1]), fmaxf(sa[qg][0][2], sa[qg][0][3])),
                       fmaxf(fmaxf(sa[qg][1][0], sa[qg][1][1]), fmaxf(sa[qg][1][2], sa[qg][1][3])));
      tm = fmaxf(tm, __shfl_xor(tm, 16));
      tm = fmaxf(tm, __shfl_xor(tm, 32));
      if (__any(tm > m_[qg])) {
        const float mnew = fmaxf(m_[qg], tm);
        const float corr = __expf(m_[qg] - mnew);
        m_[qg] = mnew;
        l_[qg] *= corr;
        f32x4 cv;
#pragma unroll
        for (int i = 0; i < 4; ++i) cv[i] = __shfl(corr, 4 * g + i);
#pragma unroll
        for (int dc = 0; dc < 8; ++dc) o[qg][dc] *= cv;
      }
      const float m = m_[qg];
      float rs = 0.f;
      bf16x8 pv;
#pragma unroll
      for (int wt = 0; wt < 2; ++wt)
#pragma unroll
        for (int i = 0; i < 4; ++i) {
          const float p = __expf(sa[qg][wt][i] - m);
          rs += p;
          pv[wt * 4 + i] = (__bf16)p;   // slot wt*4+i <-> w = 16wt + 4g + i
        }
      l_[qg] += rs;                      // per-lane partial; no shuffles here
      pa[qg] = pv;
    }

    // ---- PV ----
    __builtin_amdgcn_s_setprio(1);
#pragma unroll
    for (int dc = 0; dc < 8; ++dc) {
      const bf16x8 vb = *(const bf16x8*)(bufc + vr0 + dc * 1024);
      o[0][dc] = __builtin_amdgcn_mfma_f32_16x16x32_bf16(pa[0], vb, o[0][dc], 0, 0, 0);
      o[1][dc] = __builtin_amdgcn_mfma_f32_16x16x32_bf16(pa[1], vb, o[1][dc], 0, 0, 0);
    }
    __builtin_amdgcn_s_setprio(0);

    __syncthreads();
  }

  // ---- epilogue: reduce l, combine streams via LDS ----
  const float lam = 1.f / (1.f + __expf(-lamp[0]));
  float lt[2];
#pragma unroll
  for (int qg = 0; qg < 2; ++qg) {
    float x = l_[qg];
    x += __shfl_xor(x, 16);
    x += __shfl_xor(x, 32);
    lt[qg] = x;
  }
  if (s == 1) {
#pragma unroll
    for (int qg = 0; qg < 2; ++qg) {
      float w2[4];
#pragma unroll
      for (int i = 0; i < 4; ++i) w2[i] = lam / __shfl(lt[qg], 4 * g + i);
#pragma unroll
      for (int dc = 0; dc < 8; ++dc)
#pragma unroll
        for (int i = 0; i < 4; ++i) {
          const int ql = qh * 32 + qg * 16 + 4 * g + i;
          *(float*)(smem + ql * 512 + (dc * 16 + r) * 4) = o[qg][dc][i] * w2[i];
        }
    }
  }
  __syncthreads();
  if (s == 0) {
    float* op = Og + ((size_t)b * KQ + q0 + qh * 32) * D_DIM;
#pragma unroll
    for (int qg = 0; qg < 2; ++qg) {
      float w1[4];
#pragma unroll
      for (int i = 0; i < 4; ++i) w1[i] = 1.f / __shfl(lt[qg], 4 * g + i);
#pragma unroll
      for (int dc = 0; dc < 8; ++dc)
#pragma unroll
        for (int i = 0; i < 4; ++i) {
          const int ql = qh * 32 + qg * 16 + 4 * g + i;
          const float o2v = *(const float*)(smem + ql * 512 + (dc * 16 + r) * 4);
          op[(qg * 16 + 4 * g + i) * D_DIM + dc * 16 + r] = o[qg][dc][i] * w1[i] - o2v;
        }
    }
  }
}

extern "C" void kernel_launch(void* const* d_in, const int* in_sizes, int n_in,
                              void* d_out, int out_size, void* d_ws, size_t ws_size,
                              hipStream_t stream) {
  const float* Q1 = (const float*)d_in[0];
  const float* Q2 = (const float*)d_in[1];
  const float* K1 = (const float*)d_in[2];
  const float* K2 = (const float*)d_in[3];
  const float* V  = (const float*)d_in[4];
  const float* lm = (const float*)d_in[5];
  float* O = (float*)d_out;

  dim3 grid(B_DIM * (KQ / QBLK));  // 512 blocks, 2/CU
  dim3 block(256);
  diffattn<<<grid, block, 0, stream>>>(Q1, Q2, K1, K2, V, lm, O);
}